// Round 12
// baseline (139.145 us; speedup 1.0000x reference)
//
#include <hip/hip_runtime.h>
#include <hip/hip_bf16.h>

// MHA: B=2, S=2048, N_FEAT=1024, H=16, D=64
// r12: byte-exact resubmission of r8 (last fully-passing build, 138.99 us).
// attn: 32KB LDS, mask via pipelined register prefetch, tree-sum softmax;
// proj: z==2 epilogue transposed through LDS (coalesced V^T stores).

typedef float f32x4 __attribute__((ext_vector_type(4)));
typedef short bf16x8 __attribute__((ext_vector_type(8)));

typedef const __attribute__((address_space(1))) void* gas_ptr;
typedef __attribute__((address_space(3))) void* las_ptr;

#if __has_builtin(__builtin_amdgcn_exp2f)
#define EXP2(x) __builtin_amdgcn_exp2f(x)
#else
#define EXP2(x) exp2f(x)
#endif
#define LOG2E 1.4426950408889634f

static __device__ __forceinline__ short to_bf16s(float f) {
    __hip_bfloat16 h = __float2bfloat16(f);
    return __builtin_bit_cast(short, h);
}
// packed f32->bf16 (RNE), one instruction for two values
static __device__ __forceinline__ unsigned cvtpk(float lo, float hi) {
    unsigned r;
    asm("v_cvt_pk_bf16_f32 %0, %1, %2" : "=v"(r) : "v"(lo), "v"(hi));
    return r;
}

// ---------------- conversions ----------------
__global__ void cvt3_kernel(const float* __restrict__ s0, const float* __restrict__ s1,
                            const float* __restrict__ s2, short* __restrict__ d0,
                            short* __restrict__ d1, short* __restrict__ d2) {
    const int g = blockIdx.x;
    const int sel = g >> 12;
    const int i = (g & 4095) * 256 + threadIdx.x;
    const float* s = sel == 0 ? s0 : (sel == 1 ? s1 : s2);
    short* d = sel == 0 ? d0 : (sel == 1 ? d1 : d2);
    float4 v = reinterpret_cast<const float4*>(s)[i];
    short4 o;
    o.x = to_bf16s(v.x); o.y = to_bf16s(v.y); o.z = to_bf16s(v.z); o.w = to_bf16s(v.w);
    reinterpret_cast<short4*>(d)[i] = o;
}
__global__ void cvt4_kernel(const float* __restrict__ s0, const float* __restrict__ s1,
                            const float* __restrict__ s2, const float* __restrict__ s3,
                            short* __restrict__ d0, short* __restrict__ d1,
                            short* __restrict__ d2, short* __restrict__ d3) {
    const int g = blockIdx.x;
    const int sel = g >> 10;
    const int i = (g & 1023) * 256 + threadIdx.x;
    const float* s = sel == 0 ? s0 : (sel == 1 ? s1 : (sel == 2 ? s2 : s3));
    short* d = sel == 0 ? d0 : (sel == 1 ? d1 : (sel == 2 ? d2 : d3));
    float4 v = reinterpret_cast<const float4*>(s)[i];
    short4 o;
    o.x = to_bf16s(v.x); o.y = to_bf16s(v.y); o.z = to_bf16s(v.z); o.w = to_bf16s(v.w);
    reinterpret_cast<short4*>(d)[i] = o;
}

// mask (int 0/1) -> additive log2-domain bias, PHI-PERMUTED within each 32-key chunk
__global__ void maskf_kernel(const int* __restrict__ mask, float* __restrict__ mf) {
    const int i = blockIdx.x * 256 + threadIdx.x;
    const int p = i & 31;
    const int phi = 8 * ((p >> 2) & 3) + 4 * (p >> 4) + (p & 3);
    mf[i] = mask[(i & ~31) | phi] ? (-10000.0f * LOG2E) : 0.0f;
}

// ---------------- GEMM core: dbuf 2-phase, rowpair-interleaved LDS ----------------
static __device__ __forceinline__ void stage_tile(
    short* sa, short* sb, const short* A, const short* W,
    int m0, int n0, int k0, int tid)
{
#pragma unroll
    for (int rnd = 0; rnd < 2; ++rnd) {
        const int t = rnd * 256 + tid;
        const int c2 = t & 7;
        const int row = 2 * (t >> 3) + (c2 & 1);
        const int col = (c2 >> 1) * 8;
        __builtin_amdgcn_global_load_lds((gas_ptr)(A + (long)(m0 + row) * 1024 + k0 + col),
                                         (las_ptr)(sa + t * 8), 16, 0, 0);
        __builtin_amdgcn_global_load_lds((gas_ptr)(W + (long)(n0 + row) * 1024 + k0 + col),
                                         (las_ptr)(sb + t * 8), 16, 0, 0);
    }
}

static __device__ __forceinline__ void gemm_compute(
    const short* sa, const short* sb, int wr, int wc, int aoff, f32x4 (&acc)[4][4])
{
    bf16x8 af[4], bfr[4];
#pragma unroll
    for (int i = 0; i < 4; ++i)
        af[i] = *reinterpret_cast<const bf16x8*>(sa + (wr + i * 16) * 32 + aoff);
#pragma unroll
    for (int j = 0; j < 4; ++j)
        bfr[j] = *reinterpret_cast<const bf16x8*>(sb + (wc + j * 16) * 32 + aoff);
#pragma unroll
    for (int i = 0; i < 4; ++i)
#pragma unroll
        for (int j = 0; j < 4; ++j)
            acc[i][j] = __builtin_amdgcn_mfma_f32_16x16x32_bf16(af[i], bfr[j], acc[i][j], 0, 0, 0);
}

// fused Q/K/V projection: blockIdx.z selects; Q scaled by 0.125*log2e;
// z==2 (V^T) epilogue goes through an LDS transpose for coalesced stores.
__global__ __launch_bounds__(256, 3) void proj_gemm(
    const short* __restrict__ A0, const short* __restrict__ A1, const short* __restrict__ A2,
    const short* __restrict__ W0, const short* __restrict__ W1, const short* __restrict__ W2,
    const float* __restrict__ bi0, const float* __restrict__ bi1, const float* __restrict__ bi2,
    short* __restrict__ o0, short* __restrict__ o1, short* __restrict__ o2)
{
    __shared__ __align__(16) short smem[17408];   // 34KB: staging (32KB) / xpose 128x136
    short* sA0 = smem;
    short* sA1 = smem + 4096;
    short* sB0 = smem + 8192;
    short* sB1 = smem + 12288;

    const int z = blockIdx.z;
    const short* A = z == 0 ? A0 : (z == 1 ? A1 : A2);
    const short* W = z == 0 ? W0 : (z == 1 ? W1 : W2);
    const float* bias = z == 0 ? bi0 : (z == 1 ? bi1 : bi2);
    short* outp = z == 0 ? o0 : (z == 1 ? o1 : o2);

    const int tid = threadIdx.x;
    const int w = tid >> 6, l = tid & 63;
    const int lr = l & 15, lh = l >> 4;
    const int m0 = blockIdx.x * 128, n0 = blockIdx.y * 128;
    const int wr = (w >> 1) * 64, wc = (w & 1) * 64;
    const int aoff = (lr >> 1) * 64 + (lr & 1) * 8 + lh * 16;

    f32x4 acc[4][4] = {};

    stage_tile(sA0, sB0, A, W, m0, n0, 0, tid);
    __syncthreads();
    for (int k0 = 0; k0 < 1024; k0 += 64) {
        stage_tile(sA1, sB1, A, W, m0, n0, k0 + 32, tid);
        gemm_compute(sA0, sB0, wr, wc, aoff, acc);
        __syncthreads();
        if (k0 + 64 < 1024)
            stage_tile(sA0, sB0, A, W, m0, n0, k0 + 64, tid);
        gemm_compute(sA1, sB1, wr, wc, aoff, acc);
        __syncthreads();
    }

    if (z != 2) {
        const float scl = (z == 0) ? 0.125f * LOG2E : 1.0f;
#pragma unroll
        for (int i = 0; i < 4; ++i) {
#pragma unroll
            for (int j = 0; j < 4; ++j) {
#pragma unroll
                for (int r = 0; r < 4; ++r) {
                    const int row = m0 + wr + i * 16 + lh * 4 + r;  // b*2048+s
                    const int col = n0 + wc + j * 16 + lr;          // h*64+d
                    const float v = (acc[i][j][r] + bias[col]) * scl;
                    const int b = row >> 11, s = row & 2047;
                    const int h = col >> 6, d = col & 63;
                    outp[(((long)(b * 16 + h)) * 2048 + s) * 64 + d] = to_bf16s(v);
                }
            }
        }
    } else {
        // V^T: write bf16 tile transposed into LDS [d_local][136], then
        // coalesced stores (lane = s-direction, 256B per instruction).
#pragma unroll
        for (int i = 0; i < 4; ++i) {
#pragma unroll
            for (int j = 0; j < 4; ++j) {
                const int dl = wc + j * 16 + lr;
                const int sl = wr + i * 16 + lh * 4;
                const float bv = bias[n0 + dl];
                const unsigned w0 = cvtpk(acc[i][j][0] + bv, acc[i][j][1] + bv);
                const unsigned w1 = cvtpk(acc[i][j][2] + bv, acc[i][j][3] + bv);
                uint2 pr; pr.x = w0; pr.y = w1;
                *reinterpret_cast<uint2*>(smem + dl * 136 + sl) = pr;
            }
        }
        __syncthreads();
        const int bb = m0 >> 11;
        const int s0 = m0 & 2047;
#pragma unroll 4
        for (int rr = 0; rr < 32; ++rr) {
            const int dl = w * 32 + rr;
            const int col = n0 + dl;
            const int hh = col >> 6, dd = col & 63;
            const unsigned val = *reinterpret_cast<const unsigned*>(smem + dl * 136 + 2 * l);
            *reinterpret_cast<unsigned*>(outp + ((long)(bb * 16 + hh) * 64 + dd) * 2048 + s0 + 2 * l) = val;
        }
    }
}

// ---------------- output GEMM: 128x64 tile -> 512 blocks (2/CU), f32 epilogue ----------------
__global__ __launch_bounds__(256, 2) void out_gemm(
    const short* __restrict__ A, const short* __restrict__ W,
    const float* __restrict__ bias, float* __restrict__ outp)
{
    __shared__ __align__(16) short sa[2][4096];
    __shared__ __align__(16) short sb[2][2048];
    const int tid = threadIdx.x;
    const int w = tid >> 6, l = tid & 63;
    const int lr = l & 15, lh = l >> 4;
    const int m0 = blockIdx.x * 128, n0 = blockIdx.y * 64;
    const int wr = (w >> 1) * 64, wc = (w & 1) * 32;
    const int aoff = (lr >> 1) * 64 + (lr & 1) * 8 + lh * 16;

    f32x4 acc[4][2] = {};

    const int c2 = tid & 7;
    const int brow = 2 * (tid >> 3) + (c2 & 1);
    const int bcol = (c2 >> 1) * 8;

    auto stage = [&](short* pa, short* pb, int k0) {
#pragma unroll
        for (int rnd = 0; rnd < 2; ++rnd) {
            const int t = rnd * 256 + tid;
            const int cc = t & 7;
            const int row = 2 * (t >> 3) + (cc & 1);
            const int col = (cc >> 1) * 8;
            __builtin_amdgcn_global_load_lds((gas_ptr)(A + (long)(m0 + row) * 1024 + k0 + col),
                                             (las_ptr)(pa + t * 8), 16, 0, 0);
        }
        __builtin_amdgcn_global_load_lds((gas_ptr)(W + (long)(n0 + brow) * 1024 + k0 + bcol),
                                         (las_ptr)(pb + tid * 8), 16, 0, 0);
    };
    auto compute = [&](const short* pa, const short* pb) {
        bf16x8 af[4], bfr[2];
#pragma unroll
        for (int i = 0; i < 4; ++i)
            af[i] = *reinterpret_cast<const bf16x8*>(pa + (wr + i * 16) * 32 + aoff);
#pragma unroll
        for (int j = 0; j < 2; ++j)
            bfr[j] = *reinterpret_cast<const bf16x8*>(pb + (wc + j * 16) * 32 + aoff);
#pragma unroll
        for (int i = 0; i < 4; ++i)
#pragma unroll
            for (int j = 0; j < 2; ++j)
                acc[i][j] = __builtin_amdgcn_mfma_f32_16x16x32_bf16(af[i], bfr[j], acc[i][j], 0, 0, 0);
    };

    stage(sa[0], sb[0], 0);
    __syncthreads();
    for (int k0 = 0; k0 < 1024; k0 += 64) {
        stage(sa[1], sb[1], k0 + 32);
        compute(sa[0], sb[0]);
        __syncthreads();
        if (k0 + 64 < 1024)
            stage(sa[0], sb[0], k0 + 64);
        compute(sa[1], sb[1]);
        __syncthreads();
    }

#pragma unroll
    for (int i = 0; i < 4; ++i)
#pragma unroll
        for (int j = 0; j < 2; ++j)
#pragma unroll
            for (int r = 0; r < 4; ++r) {
                const int row = m0 + wr + i * 16 + lh * 4 + r;
                const int col = n0 + wc + j * 16 + lr;
                outp[(long)row * 1024 + col] = acc[i][j][r] + bias[col];
            }
}

// ---------------- flash attention v8 ----------------
// 1024 blocks XCD-remapped (4 heads/XCD); 4 waves x 16 q-rows; LDS 32KB ->
// >=4 blocks/CU. Mask bias via software-pipelined register prefetch (L2-hot).
// K rows phi-permuted; PV full-K MFMA with in-register P; tree-reduced softmax.

static __device__ __forceinline__ void stage_kv(
    short* ldsKb, short* ldsVb, const short* Kg, const short* Vg,
    int key0, int w, int srow, int prow, int schunk)
{
    __builtin_amdgcn_global_load_lds((gas_ptr)(Kg + (long)(key0 + prow) * 64 + schunk * 8),
                                     (las_ptr)(ldsKb + w * 512), 16, 0, 0);
    __builtin_amdgcn_global_load_lds((gas_ptr)(Kg + (long)(key0 + 32 + prow) * 64 + schunk * 8),
                                     (las_ptr)(ldsKb + 2048 + w * 512), 16, 0, 0);
    __builtin_amdgcn_global_load_lds((gas_ptr)(Vg + (long)srow * 2048 + key0 + schunk * 8),
                                     (las_ptr)(ldsVb + w * 512), 16, 0, 0);
    __builtin_amdgcn_global_load_lds((gas_ptr)(Vg + (long)(srow + 32) * 2048 + key0 + schunk * 8),
                                     (las_ptr)(ldsVb + 2048 + w * 512), 16, 0, 0);
}

static __device__ __forceinline__ void attn_step(
    const short* __restrict__ Kbuf, const short* __restrict__ Vbuf,
    const f32x4 (&mb)[4],
    const bf16x8 qf0, const bf16x8 qf1, int lr, int lh, int sw,
    float& mreg, float& lsum, f32x4 (&ao)[4])
{
    // swapped QK^T: lane holds q=lr, physical key-slot = 16s + 4lh + r;
    // mask bias is the MFMA C-init.
    f32x4 sc[4];
#pragma unroll
    for (int s = 0; s < 4; ++s) {
        const short* kb = Kbuf + (s * 16 + lr) * 64;
        bf16x8 k0 = *reinterpret_cast<const bf16x8*>(kb + (((lh * 16) ^ sw) >> 1));
        bf16x8 k1 = *reinterpret_cast<const bf16x8*>(kb + (((64 + lh * 16) ^ sw) >> 1));
        sc[s] = __builtin_amdgcn_mfma_f32_16x16x32_bf16(k0, qf0, mb[s], 0, 0, 0);
        sc[s] = __builtin_amdgcn_mfma_f32_16x16x32_bf16(k1, qf1, sc[s], 0, 0, 0);
    }

    float m0 = fmaxf(fmaxf(sc[0][0], sc[0][1]), fmaxf(sc[0][2], sc[0][3]));
    float m1 = fmaxf(fmaxf(sc[1][0], sc[1][1]), fmaxf(sc[1][2], sc[1][3]));
    float m2 = fmaxf(fmaxf(sc[2][0], sc[2][1]), fmaxf(sc[2][2], sc[2][3]));
    float m3 = fmaxf(fmaxf(sc[3][0], sc[3][1]), fmaxf(sc[3][2], sc[3][3]));
    float t = fmaxf(fmaxf(m0, m1), fmaxf(m2, m3));
    t = fmaxf(t, __shfl_xor(t, 16));
    t = fmaxf(t, __shfl_xor(t, 32));
    // defer-max: rescale only when max grew by > 8 (P bounded by 2^8)
    if (__any(t > mreg + 8.0f)) {
        const float mn = fmaxf(mreg, t);
        const float sf = EXP2(mreg - mn);
        lsum *= sf;
#pragma unroll
        for (int d4 = 0; d4 < 4; ++d4) ao[d4] *= sf;
        mreg = mn;
    }
    float e[16];
#pragma unroll
    for (int s = 0; s < 4; ++s)
#pragma unroll
        for (int r = 0; r < 4; ++r)
            e[s * 4 + r] = EXP2(sc[s][r] - mreg);
    // depth-4 tree sum
    const float e0 = (e[0] + e[1]) + (e[2] + e[3]);
    const float e1 = (e[4] + e[5]) + (e[6] + e[7]);
    const float e2 = (e[8] + e[9]) + (e[10] + e[11]);
    const float e3 = (e[12] + e[13]) + (e[14] + e[15]);
    float ps = (e0 + e1) + (e2 + e3);
    ps += __shfl_xor(ps, 16);
    ps += __shfl_xor(ps, 32);
    lsum += ps;

    // pack P into the two 16x16x32 B-frags (chunk c covers s-tiles 2c, 2c+1)
    unsigned pw[8];
#pragma unroll
    for (int i = 0; i < 8; ++i) pw[i] = cvtpk(e[2 * i], e[2 * i + 1]);
    const bf16x8 pb0 = __builtin_bit_cast(bf16x8, *(ulonglong2*)&pw[0]);
    const bf16x8 pb1 = __builtin_bit_cast(bf16x8, *(ulonglong2*)&pw[4]);

    // PV via 16x16x32: A = V^T rows (linear keys), B = pb (in-register)
#pragma unroll
    for (int c = 0; c < 2; ++c) {
        const bf16x8 pbc = c == 0 ? pb0 : pb1;
#pragma unroll
        for (int d4 = 0; d4 < 4; ++d4) {
            const short* vb = Vbuf + (d4 * 16 + lr) * 64;
            bf16x8 vf = *reinterpret_cast<const bf16x8*>(vb + (((c * 64 + lh * 16) ^ sw) >> 1));
            ao[d4] = __builtin_amdgcn_mfma_f32_16x16x32_bf16(vf, pbc, ao[d4], 0, 0, 0);
        }
    }
}

__global__ __launch_bounds__(256, 4) void attn_kernel(
    const short* __restrict__ Q, const short* __restrict__ Kmat,
    const short* __restrict__ Vt, const float* __restrict__ maskf,
    short* __restrict__ X)
{
    __shared__ __align__(16) short ldsK[2][4096];
    __shared__ __align__(16) short ldsV[2][4096];

    const int id = blockIdx.x;
    const int slot = id >> 3;
    const int bh = (id & 7) * 4 + (slot >> 5);   // XCD (id&7) serves heads 4x..4x+3
    const int q0 = (slot & 31) * 64;
    const int b = bh >> 4, h = bh & 15;
    const int w = threadIdx.x >> 6, l = threadIdx.x & 63;
    const int lr = l & 15, lh = l >> 4;
    const int sw = (lr & 7) << 4;                // read-side XOR swizzle (bytes)

    const int srow = w * 8 + (l >> 3);           // 0..31
    const int schunk = (l & 7) ^ (srow & 7);
    const int prow = 8 * ((srow >> 2) & 3) + 4 * (srow >> 4) + (srow & 3);  // phi

    const short* Kg = Kmat + (long)bh * 2048 * 64;
    const short* Vg = Vt + (long)bh * 64 * 2048;
    const float* mfp = maskf + b * 2048 + lh * 4;

    // Q B-frag (Q pre-scaled by 0.125*log2e at projection): wave owns 16 q-rows
    const short* Qp = Q + ((long)bh * 2048 + q0 + w * 16 + lr) * 64 + lh * 8;
    const bf16x8 qf0 = *reinterpret_cast<const bf16x8*>(Qp);
    const bf16x8 qf1 = *reinterpret_cast<const bf16x8*>(Qp + 32);

    float mreg = -1e30f, lsum = 0.f;
    f32x4 ao[4] = {};

    // mask-bias register prefetch, one 64-key step ahead
    f32x4 mbA[4], mbB[4];
#pragma unroll
    for (int s = 0; s < 4; ++s)
        mbA[s] = *reinterpret_cast<const f32x4*>(mfp + s * 16);

    stage_kv(ldsK[0], ldsV[0], Kg, Vg, 0, w, srow, prow, schunk);
    __syncthreads();

    for (int tt = 0; tt < 16; ++tt) {
        const int key0 = tt * 128;
#pragma unroll
        for (int s = 0; s < 4; ++s)
            mbB[s] = *reinterpret_cast<const f32x4*>(mfp + key0 + 64 + s * 16);
        stage_kv(ldsK[1], ldsV[1], Kg, Vg, key0 + 64, w, srow, prow, schunk);
        attn_step(ldsK[0], ldsV[0], mbA, qf0, qf1, lr, lh, sw, mreg, lsum, ao);
        __syncthreads();
        if (tt < 15) {
#pragma unroll
            for (int s = 0; s < 4; ++s)
                mbA[s] = *reinterpret_cast<const f32x4*>(mfp + key0 + 128 + s * 16);
            stage_kv(ldsK[0], ldsV[0], Kg, Vg, key0 + 128, w, srow, prow, schunk);
        }
        attn_step(ldsK[1], ldsV[1], mbB, qf0, qf1, lr, lh, sw, mreg, lsum, ao);
        __syncthreads();
    }

    // lane holds O^T[d = d4*16 + lh*4 + r][q = lr]
    const float inv = 1.0f / fmaxf(lsum, 1e-30f);
    const int s = q0 + w * 16 + lr;
    short* Xp = X + ((long)b * 2048 + s) * 1024 + h * 64 + lh * 4;
#pragma unroll
    for (int d4 = 0; d4 < 4; ++d4) {
        uint2 o;
        o.x = cvtpk(ao[d4][0] * inv, ao[d4][1] * inv);
        o.y = cvtpk(ao[d4][2] * inv, ao[d4][3] * inv);
        *reinterpret_cast<uint2*>(Xp + d4 * 16) = o;
    }
}

// ---------------- launch ----------------
extern "C" void kernel_launch(void* const* d_in, const int* in_sizes, int n_in,
                              void* d_out, int out_size, void* d_ws, size_t ws_size,
                              hipStream_t stream) {
    const float* query = (const float*)d_in[0];
    const float* key_  = (const float*)d_in[1];
    const float* value = (const float*)d_in[2];
    const int*   mask  = (const int*)d_in[3];
    const float* w_q = (const float*)d_in[4];
    const float* b_q = (const float*)d_in[5];
    const float* w_k = (const float*)d_in[6];
    const float* b_k = (const float*)d_in[7];
    const float* w_v = (const float*)d_in[8];
    const float* b_v = (const float*)d_in[9];
    const float* w_o = (const float*)d_in[10];
    const float* b_o = (const float*)d_in[11];

    const long SEQ = 4194304;  // 4096*1024 elements
    const long WSZ = 1048576;  // 1024*1024
    short* ws = (short*)d_ws;
    short* cq = ws;
    short* ck = cq + SEQ;
    short* cv = ck + SEQ;
    short* wq = cv + SEQ;
    short* wk = wq + WSZ;
    short* wv = wk + WSZ;
    short* wo = wv + WSZ;
    short* Qb = wo + WSZ;      // (B,H,S,64), pre-scaled by 0.125*log2e
    short* Kb = Qb + SEQ;
    short* Vt = Kb + SEQ;      // (B,H,64,S)
    short* Xb = cq;            // reuse: cq dead after projections
    float* mkf = (float*)cv;   // reuse: cv dead after projections

    cvt3_kernel<<<12288, 256, 0, stream>>>(query, key_, value, cq, ck, cv);
    cvt4_kernel<<<4096, 256, 0, stream>>>(w_q, w_k, w_v, w_o, wq, wk, wv, wo);

    dim3 blk(256);
    proj_gemm<<<dim3(32, 8, 3), blk, 0, stream>>>(cq, ck, cv, wq, wk, wv,
                                                  b_q, b_k, b_v, Qb, Kb, Vt);

    maskf_kernel<<<16, 256, 0, stream>>>(mask, mkf);  // after proj (cv reuse)

    attn_kernel<<<1024, blk, 0, stream>>>(Qb, Kb, Vt, mkf, Xb);

    out_gemm<<<dim3(32, 16), blk, 0, stream>>>(Xb, wo, b_o, (float*)d_out);
}